// Round 6
// baseline (694.426 us; speedup 1.0000x reference)
//
#include <hip/hip_runtime.h>

// Peeling propagation on bipartite graph. V=1e6, F=4.2e6, K=3 (edge e -> function e/3).
// T=5. Output: deg (V floats) in d_out.
//
// R14: delete the two-level sort. R13's setup (pack_sort 69 + transpose 4 + accum ~30
// = ~103us) existed to make 12.6M histogram increments LDS-local -- but the target
// array packed[] is only 4MB (L2-resident). Direct global atomicAdd does it in one
// streaming pass (12.6M u32 atomics over 1M addrs, ~12.6/addr, no hot spots):
//   k_zero (packed/tmp/tgrp) -> k_pack (stream inputs, emit gpack, 3 atomics/fn)
//   -> k_decode (masks from packed) -> 5 x (k_funcs, k_update).
// Also: k_funcs grid-strided at 1024 blocks (16 fns/thread) -> halves the 15.7KB
// LDS filter preload traffic (32MB -> 16MB per iter).

static constexpr int Vn = 1000000;
static constexpr int Fn = 4200000;
static constexpr int Tn = 5;

static constexpr int CH_SIZE = 4096;                       // mask-word padding granule
static constexpr int NCH = (Vn + CH_SIZE - 1) / CH_SIZE;   // 245
static constexpr int AVW = NCH * (CH_SIZE / 64);           // 15680 u64 mask words (16B-mult)

// ---- zero packed/tmp/tgrp (int4 stores) ----
__global__ __launch_bounds__(256) void k_zero(unsigned int* __restrict__ packed,
                                              unsigned int* __restrict__ tmp,
                                              unsigned char* __restrict__ tgrp)
{
    const int i = blockIdx.x * 256 + threadIdx.x;
    const int4 z = make_int4(0, 0, 0, 0);
    if (i < Vn / 4) {
        ((int4*)packed)[i] = z;
        ((int4*)tmp)[i] = z;
    }
    if (i < AVW / 16) ((int4*)tgrp)[i] = z;
}

// ---- stream pack + direct-atomic degree accumulation ----
__global__ __launch_bounds__(256) void k_pack(
    const int* __restrict__ vidx, const float* __restrict__ ef,
    const float* __restrict__ afunc,
    unsigned long long* __restrict__ gpack,
    unsigned int* __restrict__ packed)
{
    const int gid = blockIdx.x * 256 + threadIdx.x;
    const int f = 4 * gid;
    if (f >= Fn) return;                         // Fn % 4 == 0: full quads only
    const int e = 3 * f;
    int4 va = *(const int4*)(vidx + e);
    int4 vb = *(const int4*)(vidx + e + 4);
    int4 vc = *(const int4*)(vidx + e + 8);
    float4 ea = *(const float4*)(ef + e);
    float4 eb = *(const float4*)(ef + e + 4);
    float4 ec = *(const float4*)(ef + e + 8);
    float4 a4 = *(const float4*)(afunc + f);
    int      vv[12] = {va.x, va.y, va.z, va.w, vb.x, vb.y, vb.z, vb.w, vc.x, vc.y, vc.z, vc.w};
    float    ss[12] = {ea.x, ea.y, ea.z, ea.w, eb.x, eb.y, eb.z, eb.w, ec.x, ec.y, ec.z, ec.w};
    float    aa[4]  = {a4.x, a4.y, a4.z, a4.w};
    unsigned long long gq[4];
    #pragma unroll
    for (int q = 0; q < 4; ++q) {
        int v0 = vv[3 * q], v1 = vv[3 * q + 1], v2 = vv[3 * q + 2];
        unsigned int s0 = ss[3 * q]     > 0.0f ? 1u : 0u;
        unsigned int s1 = ss[3 * q + 1] > 0.0f ? 1u : 0u;
        unsigned int s2 = ss[3 * q + 2] > 0.0f ? 1u : 0u;
        unsigned int act = aa[q] != 0.0f ? 1u : 0u;
        gq[q] = (unsigned long long)(unsigned int)v0
              | ((unsigned long long)(unsigned int)v1 << 20)
              | ((unsigned long long)(unsigned int)v2 << 40)
              | ((unsigned long long)s0 << 60)
              | ((unsigned long long)s1 << 61)
              | ((unsigned long long)s2 << 62)
              | ((unsigned long long)act << 63);
        if (act) {                               // deg: cnt in high 16, pos-count low 16
            atomicAdd(&packed[v0], 0x10000u | s0);
            atomicAdd(&packed[v1], 0x10000u | s1);
            atomicAdd(&packed[v2], 0x10000u | s2);
        }
    }
    *(ulonglong2*)(gpack + f)     = make_ulonglong2(gq[0], gq[1]);
    *(ulonglong2*)(gpack + f + 2) = make_ulonglong2(gq[2], gq[3]);
}

// sub-byte dirty mask from a 64-bit singles word: bit j = (byte j of m) != 0
__device__ __forceinline__ unsigned char subdirty8(unsigned long long m) {
    unsigned char b = 0;
    #pragma unroll
    for (int j = 0; j < 8; ++j) b |= (unsigned char)((((m >> (8 * j)) & 0xFFull) ? 1u : 0u) << j);
    return b;
}

// ---- decode packed -> avm/svm/sgrp8 ----
__global__ __launch_bounds__(256) void k_decode(
    const unsigned int* __restrict__ packed,
    const float* __restrict__ avars,
    unsigned long long* __restrict__ avm,
    unsigned long long* __restrict__ svm,
    unsigned char* __restrict__ sgrp8)
{
    const int v = blockIdx.x * 256 + threadIdx.x;
    const int lane = threadIdx.x & 63;
    const bool valid = v < Vn;
    unsigned int p = valid ? packed[v] : 0u;
    bool av = valid && (avars[v] != 0.0f);
    unsigned int cnt = p >> 16, pos = p & 0xFFFFu;
    bool sv = av && (pos == 0u || pos == cnt);   // deg == |sdeg|
    unsigned long long avb = __ballot(av);
    unsigned long long svb = __ballot(sv);
    if (lane == 0 && (v >> 6) < AVW) {
        avm[v >> 6] = avb;
        svm[v >> 6] = svb;
        sgrp8[v >> 6] = subdirty8(svb);
    }
}

// ---- iteration: function side. LDS sgrp8 filter then fine bitmask. ----
__device__ __forceinline__ void fire_one(unsigned long long g, int f,
                                         unsigned long long* __restrict__ gpack,
                                         const unsigned int* __restrict__ svm32,
                                         const unsigned char* __restrict__ s8,   // LDS
                                         unsigned int* __restrict__ tmp,
                                         unsigned char* __restrict__ tgrp)
{
    if ((long long)g >= 0) return;               // inactive (bit63 clear)
    unsigned int v0 = (unsigned int)(g & 0xFFFFFu);
    unsigned int v1 = (unsigned int)((g >> 20) & 0xFFFFFu);
    unsigned int v2 = (unsigned int)((g >> 40) & 0xFFFFFu);
    // LDS-resident 8-var-granular filter: no global transactions on the common path
    unsigned int h0 = (unsigned int)(s8[v0 >> 6] >> ((v0 >> 3) & 7u)) & 1u;
    unsigned int h1 = (unsigned int)(s8[v1 >> 6] >> ((v1 >> 3) & 7u)) & 1u;
    unsigned int h2 = (unsigned int)(s8[v2 >> 6] >> ((v2 >> 3) & 7u)) & 1u;
    if (!(h0 | h1 | h2)) return;
    unsigned int hit = ((svm32[v0 >> 5] >> (v0 & 31u)) |
                        (svm32[v1 >> 5] >> (v1 & 31u)) |
                        (svm32[v2 >> 5] >> (v2 & 31u))) & 1u;
    if (!hit) return;
    gpack[f] = g & ~(1ull << 63);                // function deactivates (single_f = 1)
    atomicAdd(&tmp[v0], 0x10000u | (unsigned int)((g >> 60) & 1u));
    atomicAdd(&tmp[v1], 0x10000u | (unsigned int)((g >> 61) & 1u));
    atomicAdd(&tmp[v2], 0x10000u | (unsigned int)((g >> 62) & 1u));
    tgrp[v0 >> 6] = 1; tgrp[v1 >> 6] = 1; tgrp[v2 >> 6] = 1;
}

static constexpr int FBLOCKS = 1024;             // grid-stride blocks (4/CU)

__global__ __launch_bounds__(256) void k_funcs(unsigned long long* __restrict__ gpack,
                        const unsigned int* __restrict__ svm32,
                        const unsigned char* __restrict__ sgrp8,
                        unsigned int* __restrict__ tmp,
                        unsigned char* __restrict__ tgrp)
{
    __shared__ __align__(16) unsigned char s8[AVW];        // 15.7 KB, AVW % 16 == 0
    for (int i = threadIdx.x; i < AVW / 16; i += 256)
        ((int4*)s8)[i] = ((const int4*)sgrp8)[i];
    __syncthreads();
    const int nthr = FBLOCKS * 256;
    for (int f = (blockIdx.x * 256 + threadIdx.x) * 8; f < Fn; f += nthr * 8) {
        // Fn % 8 == 0: each 8-group is full
        ulonglong2 ga = *(const ulonglong2*)(gpack + f);   // 16B aligned
        ulonglong2 gb = *(const ulonglong2*)(gpack + f + 2);
        ulonglong2 gc = *(const ulonglong2*)(gpack + f + 4);
        ulonglong2 gd = *(const ulonglong2*)(gpack + f + 6);
        fire_one(ga.x, f,     gpack, svm32, s8, tmp, tgrp);
        fire_one(ga.y, f + 1, gpack, svm32, s8, tmp, tgrp);
        fire_one(gb.x, f + 2, gpack, svm32, s8, tmp, tgrp);
        fire_one(gb.y, f + 3, gpack, svm32, s8, tmp, tgrp);
        fire_one(gc.x, f + 4, gpack, svm32, s8, tmp, tgrp);
        fire_one(gc.y, f + 5, gpack, svm32, s8, tmp, tgrp);
        fire_one(gd.x, f + 6, gpack, svm32, s8, tmp, tgrp);
        fire_one(gd.y, f + 7, gpack, svm32, s8, tmp, tgrp);
    }
}

// ---- iteration: variable side. Clean-word early-exit; masks + sgrp8 refresh. ----
__global__ void k_update(unsigned int* __restrict__ packed,
                         unsigned int* __restrict__ tmp,
                         unsigned long long* __restrict__ avm,
                         unsigned long long* __restrict__ svm,
                         unsigned char* __restrict__ sgrp8,
                         unsigned char* __restrict__ tgrp,
                         float* __restrict__ deg, int write_deg)
{
    const int v = blockIdx.x * blockDim.x + threadIdx.x;
    const int lane = threadIdx.x & 63;
    const bool valid = v < Vn;
    unsigned long long avw = 0ull, svw = 0ull;
    unsigned char tg = 0;
    if (valid) {
        avw = avm[v >> 6]; svw = svm[v >> 6];          // wave-broadcast loads
        tg = tgrp[v >> 6];                             // wave-uniform dirty-group byte
    }
    // clean word: no fired updates, no singles to retire -> provably no state change
    if (!write_deg && !tg && svw == 0ull) return;
    const bool av_old = valid && ((avw >> lane) & 1ull);
    const bool sv     = valid && ((svw >> lane) & 1ull);
    const bool av_new = av_old && !sv;                  // av *= (1 - single_v)
    unsigned int p = 0u;
    if (valid) {
        p = packed[v];
        if (tg) {
            unsigned int tp = tmp[v];
            if (tp != 0u) {
                if (av_old) { p -= tp; packed[v] = p; } // deg -= seg*av (field-safe)
                tmp[v] = 0u;
            }
        }
    }
    const unsigned int c = p >> 16, pos = p & 0xFFFFu;
    const bool nsv = av_new && (pos == 0u || pos == c); // next single_v
    unsigned long long nsvb = __ballot(nsv);
    if (lane == 0 && valid) {
        svm[v >> 6] = nsvb;
        avm[v >> 6] = avw & ~svw;
        sgrp8[v >> 6] = subdirty8(nsvb);
        if (tg) tgrp[v >> 6] = 0;
    }
    if (write_deg && valid) deg[v] = (float)c;
}

extern "C" void kernel_launch(void* const* d_in, const int* in_sizes, int n_in,
                              void* d_out, int out_size, void* d_ws, size_t ws_size,
                              hipStream_t stream) {
    const int*   graph_map        = (const int*)d_in[0];   // row0 = vidx
    const float* edge_feature     = (const float*)d_in[1];
    const float* active_variables = (const float*)d_in[2];
    const float* active_functions = (const float*)d_in[3];
    const int* vidx = graph_map;

    float* deg = (float*)d_out;
    char* ws = (char*)d_ws;
    size_t off = 0;
    auto alloc = [&](size_t bytes) -> void* {
        void* p = ws + off; off += (bytes + 255) & ~(size_t)255; return p;
    };
    unsigned long long* gpack = (unsigned long long*)alloc(8ull * Fn);   // 33.6 MB
    unsigned int* packed      = (unsigned int*)alloc(4ull * Vn);         //  4.0 MB
    unsigned int* tmp         = (unsigned int*)alloc(4ull * Vn);         //  4.0 MB
    unsigned long long* avm   = (unsigned long long*)alloc(8ull * AVW);  //  125 KB
    unsigned long long* svm   = (unsigned long long*)alloc(8ull * AVW);  //  125 KB
    unsigned char* sgrp8      = (unsigned char*)alloc(AVW);              // 15.7 KB
    unsigned char* tgrp       = (unsigned char*)alloc(AVW);              // 15.7 KB
    // total ~42 MB

    const int BS = 256;
    const int gV = (Vn + BS - 1) / BS;
    const int gZ = (Vn / 4 + BS - 1) / BS;
    const int gP = (Fn / 4 + BS - 1) / BS;

    k_zero<<<gZ, BS, 0, stream>>>(packed, tmp, tgrp);
    k_pack<<<gP, BS, 0, stream>>>(vidx, edge_feature, active_functions, gpack, packed);
    k_decode<<<gV, BS, 0, stream>>>(packed, active_variables, avm, svm, sgrp8);
    for (int t = 0; t < Tn; ++t) {
        k_funcs<<<FBLOCKS, BS, 0, stream>>>(gpack, (const unsigned int*)svm, sgrp8, tmp, tgrp);
        k_update<<<gV, BS, 0, stream>>>(packed, tmp, avm, svm, sgrp8, tgrp, deg, (t == Tn - 1) ? 1 : 0);
    }
}

// Round 7
// 311.847 us; speedup vs baseline: 2.2268x; 2.2268x over previous
//
#include <hip/hip_runtime.h>

// Peeling propagation on bipartite graph. V=1e6, F=4.2e6, K=3 (edge e -> function e/3).
// T=5. Output: deg (V floats) in d_out.
//
// R15 = R13 (312us, best) consolidated:
//  * k_funcs grid-strided at 1024 blocks (8 fns/thread, 2 sweeps): halves the 15.7KB
//    LDS filter preload traffic per iteration and per-block fixed costs.
//  * tmp/tgrp zeroing moved from k_pack_sort tail into k_accum epilogue (rides the
//    existing per-v pass; pack_sort returns to its measured-65.5us R9 form).
// R14 lesson (banked): scattered global atomics are memory-side on MI355X (~32B HBM
// write per atomic, 426MB for 12.6M) -- the LDS-localizing sort is the right setup.
// R12 lesson: grid.sync ~240us each; never cooperative-sync this problem.

static constexpr int Vn = 1000000;
static constexpr int Fn = 4200000;
static constexpr int Tn = 5;

static constexpr int SBLK = 2048;                          // sort blocks / regions
static constexpr int FPB  = 2052;                          // functions/block (mult of 4)
static constexpr int BIN_BITS = 10;                        // fine bin = 1024 vars
static constexpr int BIN_SIZE = 1 << BIN_BITS;
static constexpr int NB  = (Vn + BIN_SIZE - 1) >> BIN_BITS;   // 977 fine bins
static constexpr int NBP = 1024;                           // padded fine-bin count (scan)
static constexpr int CH_BITS = 12;                         // chunk = 4096 vars
static constexpr int CH_SIZE = 1 << CH_BITS;
static constexpr int NCH = (Vn + CH_SIZE - 1) >> CH_BITS;  // 245 chunks
static constexpr int RCAP = 3 * FPB;                       // 6156 max entries/region
static constexpr int RSTRIDE = (RCAP + 63) & ~63;          // 6208 -> 128B-aligned regions
static constexpr int OROW = 1024;                          // offs row stride (u16)
static constexpr int AVW = NCH * (CH_SIZE / 64);           // 15680 u64 mask words (16B-mult)

// ---- fused pack + histogram + shuffle-scan + LDS-staged scatter + coalesced flush ----
__global__ __launch_bounds__(256) void k_pack_sort(
    const int* __restrict__ vidx, const float* __restrict__ ef,
    const float* __restrict__ afunc,
    unsigned long long* __restrict__ gpack,
    unsigned short* __restrict__ offs,      // [SBLK][OROW] exclusive fine-bin offsets
    unsigned short* __restrict__ sorted)    // [SBLK][RSTRIDE] block-private regions
{
    __shared__ unsigned int hist[NBP];
    __shared__ unsigned int cur[NBP];
    __shared__ unsigned int wsum[4];
    __shared__ unsigned int s_total;
    __shared__ __align__(16) unsigned short st[RSTRIDE];   // 12.4 KB staged region

    const int k = blockIdx.x;
    const int f0 = k * FPB;
    int n = Fn - f0; if (n < 0) n = 0; if (n > FPB) n = FPB;
    const int n4 = n >> 2;

    for (int i = threadIdx.x; i < NBP; i += 256) hist[i] = 0u;
    __syncthreads();

    // pass 1 (4-wide): read vidx/ef/afunc once, emit gpack, histogram fine bins
    for (int j = threadIdx.x; j < n4; j += 256) {
        const int fb = f0 + 4 * j, e = 3 * fb;
        int4 va = *(const int4*)(vidx + e);
        int4 vb = *(const int4*)(vidx + e + 4);
        int4 vc = *(const int4*)(vidx + e + 8);
        float4 ea = *(const float4*)(ef + e);
        float4 eb = *(const float4*)(ef + e + 4);
        float4 ec = *(const float4*)(ef + e + 8);
        float4 a4 = *(const float4*)(afunc + fb);
        int      vv[12] = {va.x, va.y, va.z, va.w, vb.x, vb.y, vb.z, vb.w, vc.x, vc.y, vc.z, vc.w};
        float    ss[12] = {ea.x, ea.y, ea.z, ea.w, eb.x, eb.y, eb.z, eb.w, ec.x, ec.y, ec.z, ec.w};
        float    aa[4]  = {a4.x, a4.y, a4.z, a4.w};
        unsigned long long gq[4];
        #pragma unroll
        for (int q = 0; q < 4; ++q) {
            int v0 = vv[3 * q], v1 = vv[3 * q + 1], v2 = vv[3 * q + 2];
            unsigned int s0 = ss[3 * q]     > 0.0f ? 1u : 0u;
            unsigned int s1 = ss[3 * q + 1] > 0.0f ? 1u : 0u;
            unsigned int s2 = ss[3 * q + 2] > 0.0f ? 1u : 0u;
            unsigned int act = aa[q] != 0.0f ? 1u : 0u;
            gq[q] = (unsigned long long)(unsigned int)v0
                  | ((unsigned long long)(unsigned int)v1 << 20)
                  | ((unsigned long long)(unsigned int)v2 << 40)
                  | ((unsigned long long)s0 << 60)
                  | ((unsigned long long)s1 << 61)
                  | ((unsigned long long)s2 << 62)
                  | ((unsigned long long)act << 63);
            if (act) {
                atomicAdd(&hist[v0 >> BIN_BITS], 1u);
                atomicAdd(&hist[v1 >> BIN_BITS], 1u);
                atomicAdd(&hist[v2 >> BIN_BITS], 1u);
            }
        }
        *(ulonglong2*)(gpack + fb)     = make_ulonglong2(gq[0], gq[1]);
        *(ulonglong2*)(gpack + fb + 2) = make_ulonglong2(gq[2], gq[3]);
    }
    // scalar tail (0..3 functions)
    for (int i = 4 * n4 + threadIdx.x; i < n; i += 256) {
        const int f = f0 + i, e0 = 3 * f;
        int v0 = vidx[e0], v1 = vidx[e0 + 1], v2 = vidx[e0 + 2];
        unsigned int s0 = ef[e0]     > 0.0f ? 1u : 0u;
        unsigned int s1 = ef[e0 + 1] > 0.0f ? 1u : 0u;
        unsigned int s2 = ef[e0 + 2] > 0.0f ? 1u : 0u;
        unsigned int act = afunc[f] != 0.0f ? 1u : 0u;
        unsigned long long g = (unsigned long long)(unsigned int)v0
                             | ((unsigned long long)(unsigned int)v1 << 20)
                             | ((unsigned long long)(unsigned int)v2 << 40)
                             | ((unsigned long long)s0 << 60)
                             | ((unsigned long long)s1 << 61)
                             | ((unsigned long long)s2 << 62)
                             | ((unsigned long long)act << 63);
        gpack[f] = g;
        if (act) {
            atomicAdd(&hist[v0 >> BIN_BITS], 1u);
            atomicAdd(&hist[v1 >> BIN_BITS], 1u);
            atomicAdd(&hist[v2 >> BIN_BITS], 1u);
        }
    }
    __syncthreads();

    // shuffle-based exclusive scan over 1024 fine bins (256 threads x 4 bins)
    {
        const int t = threadIdx.x, lane = t & 63, wid = t >> 6;
        unsigned int a0 = hist[4 * t], a1 = hist[4 * t + 1];
        unsigned int a2 = hist[4 * t + 2], a3 = hist[4 * t + 3];
        unsigned int tsum = a0 + a1 + a2 + a3;
        unsigned int x = tsum;
        #pragma unroll
        for (int off = 1; off < 64; off <<= 1) {
            unsigned int y = (unsigned int)__shfl_up((int)x, off);
            if (lane >= off) x += y;
        }
        if (lane == 63) wsum[wid] = x;
        __syncthreads();
        unsigned int wbase = 0;
        for (int w = 0; w < wid; ++w) wbase += wsum[w];
        unsigned int e0x = wbase + x - tsum;      // exclusive prefix of bin 4t
        unsigned int e1x = e0x + a0, e2x = e1x + a1, e3x = e2x + a2;
        cur[4 * t] = e0x; cur[4 * t + 1] = e1x; cur[4 * t + 2] = e2x; cur[4 * t + 3] = e3x;
        if (t == 255) s_total = e3x + a3;         // inclusive total (= #active entries)
        unsigned short* row = offs + (size_t)k * OROW;
        if (4 * t     <= NB) row[4 * t]     = (unsigned short)e0x;
        if (4 * t + 1 <= NB) row[4 * t + 1] = (unsigned short)e1x;
        if (4 * t + 2 <= NB) row[4 * t + 2] = (unsigned short)e2x;
        if (4 * t + 3 <= NB) row[4 * t + 3] = (unsigned short)e3x;
    }
    __syncthreads();

    // pass 2 (4-wide): re-read gpack (cache-hot) and scatter into LDS region;
    // entry = 12-bit chunk-local v | sign<<12
    for (int j = threadIdx.x; j < n4; j += 256) {
        const int fb = f0 + 4 * j;
        ulonglong2 ga = *(const ulonglong2*)(gpack + fb);
        ulonglong2 gb = *(const ulonglong2*)(gpack + fb + 2);
        unsigned long long gq[4] = {ga.x, ga.y, gb.x, gb.y};
        #pragma unroll
        for (int q = 0; q < 4; ++q) {
            unsigned long long g = gq[q];
            if ((long long)g < 0) {
                unsigned int v0 = (unsigned int)(g & 0xFFFFFu);
                unsigned int v1 = (unsigned int)((g >> 20) & 0xFFFFFu);
                unsigned int v2 = (unsigned int)((g >> 40) & 0xFFFFFu);
                unsigned int sl0 = atomicAdd(&cur[v0 >> BIN_BITS], 1u);
                st[sl0] = (unsigned short)((v0 & (CH_SIZE - 1)) | ((unsigned int)((g >> 60) & 1u) << CH_BITS));
                unsigned int sl1 = atomicAdd(&cur[v1 >> BIN_BITS], 1u);
                st[sl1] = (unsigned short)((v1 & (CH_SIZE - 1)) | ((unsigned int)((g >> 61) & 1u) << CH_BITS));
                unsigned int sl2 = atomicAdd(&cur[v2 >> BIN_BITS], 1u);
                st[sl2] = (unsigned short)((v2 & (CH_SIZE - 1)) | ((unsigned int)((g >> 62) & 1u) << CH_BITS));
            }
        }
    }
    for (int i = 4 * n4 + threadIdx.x; i < n; i += 256) {
        unsigned long long g = gpack[f0 + i];
        if ((long long)g < 0) {
            unsigned int v0 = (unsigned int)(g & 0xFFFFFu);
            unsigned int v1 = (unsigned int)((g >> 20) & 0xFFFFFu);
            unsigned int v2 = (unsigned int)((g >> 40) & 0xFFFFFu);
            unsigned int sl0 = atomicAdd(&cur[v0 >> BIN_BITS], 1u);
            st[sl0] = (unsigned short)((v0 & (CH_SIZE - 1)) | ((unsigned int)((g >> 60) & 1u) << CH_BITS));
            unsigned int sl1 = atomicAdd(&cur[v1 >> BIN_BITS], 1u);
            st[sl1] = (unsigned short)((v1 & (CH_SIZE - 1)) | ((unsigned int)((g >> 61) & 1u) << CH_BITS));
            unsigned int sl2 = atomicAdd(&cur[v2 >> BIN_BITS], 1u);
            st[sl2] = (unsigned short)((v2 & (CH_SIZE - 1)) | ((unsigned int)((g >> 62) & 1u) << CH_BITS));
        }
    }
    __syncthreads();

    // coalesced flush: LDS region -> global, 16B vectors (slack beyond total never read)
    {
        const int tot = (int)s_total;
        const int nvec = (tot + 7) >> 3;               // 8 u16 per int4
        int4* __restrict__ dst = (int4*)(sorted + (size_t)k * RSTRIDE);  // RSTRIDE*2 % 16 == 0
        const int4* __restrict__ src = (const int4*)st;
        for (int i = threadIdx.x; i < nvec; i += 256) dst[i] = src[i];
    }
}

// ---- tiled transpose: offs [SBLK][1024] -> offs_T [1024][SBLK] ----
__global__ __launch_bounds__(256) void k_transpose(const unsigned short* __restrict__ in,
                                                   unsigned short* __restrict__ out) {
    __shared__ unsigned short t[64][65];
    const int bx = blockIdx.x;   // 16 col tiles (1024/64)
    const int by = blockIdx.y;   // 32 row tiles (2048/64)
    for (int i = threadIdx.x; i < 64 * 64; i += 256) {
        int r = i >> 6, c = i & 63;
        t[r][c] = in[(size_t)(by * 64 + r) * OROW + (bx * 64 + c)];
    }
    __syncthreads();
    for (int i = threadIdx.x; i < 64 * 64; i += 256) {
        int r = i >> 6, c = i & 63;
        out[(size_t)(bx * 64 + r) * SBLK + (by * 64 + c)] = t[c][r];
    }
}

// sub-byte dirty mask from a 64-bit singles word: bit j = (byte j of m) != 0
__device__ __forceinline__ unsigned char subdirty8(unsigned long long m) {
    unsigned char b = 0;
    #pragma unroll
    for (int j = 0; j < 8; ++j) b |= (unsigned char)((((m >> (8 * j)) & 0xFFull) ? 1u : 0u) << j);
    return b;
}

// ---- per-chunk accumulate + decode + tmp/tgrp zeroing epilogue ----
__global__ __launch_bounds__(1024) void k_accum(
    const unsigned short* __restrict__ offs_T,   // [1024][SBLK]
    const unsigned short* __restrict__ sorted,
    const float* __restrict__ avars,
    unsigned int* __restrict__ packed,
    unsigned long long* __restrict__ avm,
    unsigned long long* __restrict__ svm,
    unsigned char* __restrict__ sgrp8,
    unsigned int* __restrict__ tmp,
    unsigned char* __restrict__ tgrp)
{
    __shared__ unsigned int acc[CH_SIZE];        // 16 KB
    __shared__ unsigned short row0[SBLK];        // 4 KB
    __shared__ unsigned short row1[SBLK];        // 4 KB
    const int c = blockIdx.x;                    // chunk 0..244
    const int r0 = 4 * c;
    const int r1 = (4 * c + 4 < NB) ? (4 * c + 4) : NB;
    for (int i = threadIdx.x; i < CH_SIZE; i += 1024) acc[i] = 0u;
    for (int i = threadIdx.x; i < SBLK; i += 1024) {
        row0[i] = offs_T[(size_t)r0 * SBLK + i];
        row1[i] = offs_T[(size_t)r1 * SBLK + i];
    }
    __syncthreads();
    for (int k = threadIdx.x; k < SBLK; k += 1024) {   // 2 regions per thread
        const int s0 = row0[k], s1 = row1[k];
        const unsigned short* seg = sorted + (size_t)k * RSTRIDE;  // 128B-aligned base
        int e = s0;
        for (; e < s1 && (e & 3); ++e) {               // head to 8B alignment
            unsigned int p = seg[e];
            atomicAdd(&acc[p & (CH_SIZE - 1)], 0x10000u | (p >> CH_BITS));
        }
        for (; e + 4 <= s1; e += 4) {                  // 4 entries per u64 load
            unsigned long long q = *(const unsigned long long*)(seg + e);
            #pragma unroll
            for (int j = 0; j < 4; ++j) {
                unsigned int p = (unsigned int)((q >> (16 * j)) & 0xFFFFu);
                atomicAdd(&acc[p & (CH_SIZE - 1)], 0x10000u | (p >> CH_BITS));
            }
        }
        for (; e < s1; ++e) {                          // tail
            unsigned int p = seg[e];
            atomicAdd(&acc[p & (CH_SIZE - 1)], 0x10000u | (p >> CH_BITS));
        }
    }
    __syncthreads();
    const int vbase = c << CH_BITS;
    for (int i = threadIdx.x; i < CH_SIZE; i += 1024) {
        int v = vbase + i;
        bool valid = v < Vn;
        unsigned int p = valid ? acc[i] : 0u;
        bool av = valid && (avars[v] != 0.0f);
        unsigned int cnt = p >> 16, pos = p & 0xFFFFu;
        bool sv = av && (pos == 0u || pos == cnt);    // deg == |sdeg|
        unsigned long long avb = __ballot(av);
        unsigned long long svb = __ballot(sv);
        if (valid) { packed[v] = p; tmp[v] = 0u; }    // tmp zeroed here (rides the pass)
        if ((threadIdx.x & 63) == 0) {                // word index < AVW (chunk-padded)
            avm[v >> 6] = avb;
            svm[v >> 6] = svb;
            sgrp8[v >> 6] = subdirty8(svb);           // 8-var-granular dirty bits
            tgrp[v >> 6] = 0;
        }
    }
}

// ---- iteration: function side. LDS sgrp8 filter then fine bitmask. ----
__device__ __forceinline__ void fire_one(unsigned long long g, int f,
                                         unsigned long long* __restrict__ gpack,
                                         const unsigned int* __restrict__ svm32,
                                         const unsigned char* __restrict__ s8,   // LDS
                                         unsigned int* __restrict__ tmp,
                                         unsigned char* __restrict__ tgrp)
{
    if ((long long)g >= 0) return;               // inactive (bit63 clear)
    unsigned int v0 = (unsigned int)(g & 0xFFFFFu);
    unsigned int v1 = (unsigned int)((g >> 20) & 0xFFFFFu);
    unsigned int v2 = (unsigned int)((g >> 40) & 0xFFFFFu);
    // LDS-resident 8-var-granular filter: no global transactions on the common path
    unsigned int h0 = (unsigned int)(s8[v0 >> 6] >> ((v0 >> 3) & 7u)) & 1u;
    unsigned int h1 = (unsigned int)(s8[v1 >> 6] >> ((v1 >> 3) & 7u)) & 1u;
    unsigned int h2 = (unsigned int)(s8[v2 >> 6] >> ((v2 >> 3) & 7u)) & 1u;
    if (!(h0 | h1 | h2)) return;
    unsigned int hit = ((svm32[v0 >> 5] >> (v0 & 31u)) |
                        (svm32[v1 >> 5] >> (v1 & 31u)) |
                        (svm32[v2 >> 5] >> (v2 & 31u))) & 1u;
    if (!hit) return;
    gpack[f] = g & ~(1ull << 63);                // function deactivates (single_f = 1)
    atomicAdd(&tmp[v0], 0x10000u | (unsigned int)((g >> 60) & 1u));
    atomicAdd(&tmp[v1], 0x10000u | (unsigned int)((g >> 61) & 1u));
    atomicAdd(&tmp[v2], 0x10000u | (unsigned int)((g >> 62) & 1u));
    tgrp[v0 >> 6] = 1; tgrp[v1 >> 6] = 1; tgrp[v2 >> 6] = 1;
}

static constexpr int FBLOCKS = 1024;             // grid-stride blocks (4/CU)

__global__ __launch_bounds__(256) void k_funcs(unsigned long long* __restrict__ gpack,
                        const unsigned int* __restrict__ svm32,
                        const unsigned char* __restrict__ sgrp8,
                        unsigned int* __restrict__ tmp,
                        unsigned char* __restrict__ tgrp)
{
    __shared__ __align__(16) unsigned char s8[AVW];        // 15.7 KB, AVW % 16 == 0
    for (int i = threadIdx.x; i < AVW / 16; i += 256)
        ((int4*)s8)[i] = ((const int4*)sgrp8)[i];
    __syncthreads();
    const int step = FBLOCKS * 256 * 8;
    for (int f = (blockIdx.x * 256 + threadIdx.x) * 8; f < Fn; f += step) {
        // Fn % 8 == 0: each 8-group is full
        ulonglong2 ga = *(const ulonglong2*)(gpack + f);   // 16B aligned
        ulonglong2 gb = *(const ulonglong2*)(gpack + f + 2);
        ulonglong2 gc = *(const ulonglong2*)(gpack + f + 4);
        ulonglong2 gd = *(const ulonglong2*)(gpack + f + 6);
        fire_one(ga.x, f,     gpack, svm32, s8, tmp, tgrp);
        fire_one(ga.y, f + 1, gpack, svm32, s8, tmp, tgrp);
        fire_one(gb.x, f + 2, gpack, svm32, s8, tmp, tgrp);
        fire_one(gb.y, f + 3, gpack, svm32, s8, tmp, tgrp);
        fire_one(gc.x, f + 4, gpack, svm32, s8, tmp, tgrp);
        fire_one(gc.y, f + 5, gpack, svm32, s8, tmp, tgrp);
        fire_one(gd.x, f + 6, gpack, svm32, s8, tmp, tgrp);
        fire_one(gd.y, f + 7, gpack, svm32, s8, tmp, tgrp);
    }
}

// ---- iteration: variable side. Clean-word early-exit; masks + sgrp8 refresh. ----
__global__ void k_update(unsigned int* __restrict__ packed,
                         unsigned int* __restrict__ tmp,
                         unsigned long long* __restrict__ avm,
                         unsigned long long* __restrict__ svm,
                         unsigned char* __restrict__ sgrp8,
                         unsigned char* __restrict__ tgrp,
                         float* __restrict__ deg, int write_deg)
{
    const int v = blockIdx.x * blockDim.x + threadIdx.x;
    const int lane = threadIdx.x & 63;
    const bool valid = v < Vn;
    unsigned long long avw = 0ull, svw = 0ull;
    unsigned char tg = 0;
    if (valid) {
        avw = avm[v >> 6]; svw = svm[v >> 6];          // wave-broadcast loads
        tg = tgrp[v >> 6];                             // wave-uniform dirty-group byte
    }
    // clean word: no fired updates, no singles to retire -> provably no state change
    if (!write_deg && !tg && svw == 0ull) return;
    const bool av_old = valid && ((avw >> lane) & 1ull);
    const bool sv     = valid && ((svw >> lane) & 1ull);
    const bool av_new = av_old && !sv;                  // av *= (1 - single_v)
    unsigned int p = 0u;
    if (valid) {
        p = packed[v];
        if (tg) {
            unsigned int tp = tmp[v];
            if (tp != 0u) {
                if (av_old) { p -= tp; packed[v] = p; } // deg -= seg*av (field-safe)
                tmp[v] = 0u;
            }
        }
    }
    const unsigned int c = p >> 16, pos = p & 0xFFFFu;
    const bool nsv = av_new && (pos == 0u || pos == c); // next single_v
    unsigned long long nsvb = __ballot(nsv);
    if (lane == 0 && valid) {
        svm[v >> 6] = nsvb;
        avm[v >> 6] = avw & ~svw;
        sgrp8[v >> 6] = subdirty8(nsvb);
        if (tg) tgrp[v >> 6] = 0;
    }
    if (write_deg && valid) deg[v] = (float)c;
}

extern "C" void kernel_launch(void* const* d_in, const int* in_sizes, int n_in,
                              void* d_out, int out_size, void* d_ws, size_t ws_size,
                              hipStream_t stream) {
    const int*   graph_map        = (const int*)d_in[0];   // row0 = vidx
    const float* edge_feature     = (const float*)d_in[1];
    const float* active_variables = (const float*)d_in[2];
    const float* active_functions = (const float*)d_in[3];
    const int* vidx = graph_map;

    float* deg = (float*)d_out;
    char* ws = (char*)d_ws;
    size_t off = 0;
    auto alloc = [&](size_t bytes) -> void* {
        void* p = ws + off; off += (bytes + 255) & ~(size_t)255; return p;
    };
    unsigned long long* gpack = (unsigned long long*)alloc(8ull * Fn);            // 33.6 MB
    unsigned int* packed      = (unsigned int*)alloc(4ull * Vn);                  //  4.0 MB
    unsigned long long* avm   = (unsigned long long*)alloc(8ull * AVW);           //  125 KB
    unsigned long long* svm   = (unsigned long long*)alloc(8ull * AVW);           //  125 KB
    unsigned char* sgrp8      = (unsigned char*)alloc(AVW);                       // 15.7 KB
    unsigned char* tgrp       = (unsigned char*)alloc(AVW);                       // 15.7 KB
    unsigned short* offs      = (unsigned short*)alloc(2ull * SBLK * OROW);       //  4.2 MB
    unsigned short* offs_T    = (unsigned short*)alloc(2ull * SBLK * OROW);       //  4.2 MB
    unsigned short* sorted    = (unsigned short*)alloc(2ull * SBLK * RSTRIDE);    // 25.4 MB
    unsigned int* tmp         = (unsigned int*)alloc(4ull * Vn);                  //  4.0 MB
    // total ~75.7 MB

    const int BS = 256;
    const int gV = (Vn + BS - 1) / BS;

    k_pack_sort<<<SBLK, 256, 0, stream>>>(vidx, edge_feature, active_functions,
                                          gpack, offs, sorted);
    k_transpose<<<dim3(OROW / 64, SBLK / 64), 256, 0, stream>>>(offs, offs_T);
    k_accum<<<NCH, 1024, 0, stream>>>(offs_T, sorted, active_variables, packed,
                                      avm, svm, sgrp8, tmp, tgrp);
    for (int t = 0; t < Tn; ++t) {
        k_funcs<<<FBLOCKS, BS, 0, stream>>>(gpack, (const unsigned int*)svm, sgrp8, tmp, tgrp);
        k_update<<<gV, BS, 0, stream>>>(packed, tmp, avm, svm, sgrp8, tgrp, deg, (t == Tn - 1) ? 1 : 0);
    }
}

// Round 8
// 304.588 us; speedup vs baseline: 2.2799x; 1.0238x over previous
//
#include <hip/hip_runtime.h>

// Peeling propagation on bipartite graph. V=1e6, F=4.2e6, K=3 (edge e -> function e/3).
// T=5. Output: deg (V floats) in d_out.
//
// R16 = R15 (311.8us best) minus one dispatch and plus occupancy:
//  * k_transpose deleted: k_accum reads offs rows directly (strided u16 loads,
//    ~1M extra transactions ~1us vs ~14us saved). 13 -> 12 dispatches.
//  * k_pack_sort: hist merged into cur (histogram in place; scan overwrites with
//    cursors) -> LDS 21KB -> ~16.9KB -> 8 blocks/CU (was 7). Dead scalar tails
//    removed (Fn%4==0 and FPB%4==0 imply n%4==0 for every block).
// Model: ~180us kernel work + ~10us/dispatch overhead; 12 dispatches is the floor
// for the Jacobi structure (grid.sync measured ~240us/sync in R12 -- never again).
// R14 lesson: scattered global atomics are memory-side (~32B HBM write each).

static constexpr int Vn = 1000000;
static constexpr int Fn = 4200000;
static constexpr int Tn = 5;

static constexpr int SBLK = 2048;                          // sort blocks / regions
static constexpr int FPB  = 2052;                          // functions/block (mult of 4)
static constexpr int BIN_BITS = 10;                        // fine bin = 1024 vars
static constexpr int BIN_SIZE = 1 << BIN_BITS;
static constexpr int NB  = (Vn + BIN_SIZE - 1) >> BIN_BITS;   // 977 fine bins
static constexpr int NBP = 1024;                           // padded fine-bin count (scan)
static constexpr int CH_BITS = 12;                         // chunk = 4096 vars
static constexpr int CH_SIZE = 1 << CH_BITS;
static constexpr int NCH = (Vn + CH_SIZE - 1) >> CH_BITS;  // 245 chunks
static constexpr int RCAP = 3 * FPB;                       // 6156 max entries/region
static constexpr int RSTRIDE = (RCAP + 63) & ~63;          // 6208 -> 128B-aligned regions
static constexpr int OROW = 1024;                          // offs row stride (u16)
static constexpr int AVW = NCH * (CH_SIZE / 64);           // 15680 u64 mask words (16B-mult)

// ---- fused pack + histogram + shuffle-scan + LDS-staged scatter + coalesced flush ----
__global__ __launch_bounds__(256) void k_pack_sort(
    const int* __restrict__ vidx, const float* __restrict__ ef,
    const float* __restrict__ afunc,
    unsigned long long* __restrict__ gpack,
    unsigned short* __restrict__ offs,      // [SBLK][OROW] exclusive fine-bin offsets
    unsigned short* __restrict__ sorted)    // [SBLK][RSTRIDE] block-private regions
{
    __shared__ unsigned int cur[NBP];       // pass1: histogram; after scan: cursors
    __shared__ unsigned int wsum[4];
    __shared__ unsigned int s_total;
    __shared__ __align__(16) unsigned short st[RSTRIDE];   // 12.4 KB staged region
    // LDS total ~16.6 KB -> 8 blocks/CU (32 waves)

    const int k = blockIdx.x;
    const int f0 = k * FPB;
    int n = Fn - f0; if (n < 0) n = 0; if (n > FPB) n = FPB;
    const int n4 = n >> 2;                  // n % 4 == 0 always (Fn, FPB mult of 4)

    for (int i = threadIdx.x; i < NBP; i += 256) cur[i] = 0u;
    __syncthreads();

    // pass 1 (4-wide): read vidx/ef/afunc once, emit gpack, histogram fine bins
    for (int j = threadIdx.x; j < n4; j += 256) {
        const int fb = f0 + 4 * j, e = 3 * fb;
        int4 va = *(const int4*)(vidx + e);
        int4 vb = *(const int4*)(vidx + e + 4);
        int4 vc = *(const int4*)(vidx + e + 8);
        float4 ea = *(const float4*)(ef + e);
        float4 eb = *(const float4*)(ef + e + 4);
        float4 ec = *(const float4*)(ef + e + 8);
        float4 a4 = *(const float4*)(afunc + fb);
        int      vv[12] = {va.x, va.y, va.z, va.w, vb.x, vb.y, vb.z, vb.w, vc.x, vc.y, vc.z, vc.w};
        float    ss[12] = {ea.x, ea.y, ea.z, ea.w, eb.x, eb.y, eb.z, eb.w, ec.x, ec.y, ec.z, ec.w};
        float    aa[4]  = {a4.x, a4.y, a4.z, a4.w};
        unsigned long long gq[4];
        #pragma unroll
        for (int q = 0; q < 4; ++q) {
            int v0 = vv[3 * q], v1 = vv[3 * q + 1], v2 = vv[3 * q + 2];
            unsigned int s0 = ss[3 * q]     > 0.0f ? 1u : 0u;
            unsigned int s1 = ss[3 * q + 1] > 0.0f ? 1u : 0u;
            unsigned int s2 = ss[3 * q + 2] > 0.0f ? 1u : 0u;
            unsigned int act = aa[q] != 0.0f ? 1u : 0u;
            gq[q] = (unsigned long long)(unsigned int)v0
                  | ((unsigned long long)(unsigned int)v1 << 20)
                  | ((unsigned long long)(unsigned int)v2 << 40)
                  | ((unsigned long long)s0 << 60)
                  | ((unsigned long long)s1 << 61)
                  | ((unsigned long long)s2 << 62)
                  | ((unsigned long long)act << 63);
            if (act) {
                atomicAdd(&cur[v0 >> BIN_BITS], 1u);
                atomicAdd(&cur[v1 >> BIN_BITS], 1u);
                atomicAdd(&cur[v2 >> BIN_BITS], 1u);
            }
        }
        *(ulonglong2*)(gpack + fb)     = make_ulonglong2(gq[0], gq[1]);
        *(ulonglong2*)(gpack + fb + 2) = make_ulonglong2(gq[2], gq[3]);
    }
    __syncthreads();

    // shuffle-based exclusive scan over 1024 fine bins (256 threads x 4 bins).
    // Each thread reads only its own cur[4t..4t+3] before overwriting them.
    {
        const int t = threadIdx.x, lane = t & 63, wid = t >> 6;
        unsigned int a0 = cur[4 * t], a1 = cur[4 * t + 1];
        unsigned int a2 = cur[4 * t + 2], a3 = cur[4 * t + 3];
        unsigned int tsum = a0 + a1 + a2 + a3;
        unsigned int x = tsum;
        #pragma unroll
        for (int off = 1; off < 64; off <<= 1) {
            unsigned int y = (unsigned int)__shfl_up((int)x, off);
            if (lane >= off) x += y;
        }
        if (lane == 63) wsum[wid] = x;
        __syncthreads();
        unsigned int wbase = 0;
        for (int w = 0; w < wid; ++w) wbase += wsum[w];
        unsigned int e0x = wbase + x - tsum;      // exclusive prefix of bin 4t
        unsigned int e1x = e0x + a0, e2x = e1x + a1, e3x = e2x + a2;
        cur[4 * t] = e0x; cur[4 * t + 1] = e1x; cur[4 * t + 2] = e2x; cur[4 * t + 3] = e3x;
        if (t == 255) s_total = e3x + a3;         // inclusive total (= #active entries)
        unsigned short* row = offs + (size_t)k * OROW;
        if (4 * t     <= NB) row[4 * t]     = (unsigned short)e0x;
        if (4 * t + 1 <= NB) row[4 * t + 1] = (unsigned short)e1x;
        if (4 * t + 2 <= NB) row[4 * t + 2] = (unsigned short)e2x;
        if (4 * t + 3 <= NB) row[4 * t + 3] = (unsigned short)e3x;
    }
    __syncthreads();

    // pass 2 (4-wide): re-read gpack (L2-hot) and scatter into LDS region;
    // entry = 12-bit chunk-local v | sign<<12
    for (int j = threadIdx.x; j < n4; j += 256) {
        const int fb = f0 + 4 * j;
        ulonglong2 ga = *(const ulonglong2*)(gpack + fb);
        ulonglong2 gb = *(const ulonglong2*)(gpack + fb + 2);
        unsigned long long gq[4] = {ga.x, ga.y, gb.x, gb.y};
        #pragma unroll
        for (int q = 0; q < 4; ++q) {
            unsigned long long g = gq[q];
            if ((long long)g < 0) {
                unsigned int v0 = (unsigned int)(g & 0xFFFFFu);
                unsigned int v1 = (unsigned int)((g >> 20) & 0xFFFFFu);
                unsigned int v2 = (unsigned int)((g >> 40) & 0xFFFFFu);
                unsigned int sl0 = atomicAdd(&cur[v0 >> BIN_BITS], 1u);
                st[sl0] = (unsigned short)((v0 & (CH_SIZE - 1)) | ((unsigned int)((g >> 60) & 1u) << CH_BITS));
                unsigned int sl1 = atomicAdd(&cur[v1 >> BIN_BITS], 1u);
                st[sl1] = (unsigned short)((v1 & (CH_SIZE - 1)) | ((unsigned int)((g >> 61) & 1u) << CH_BITS));
                unsigned int sl2 = atomicAdd(&cur[v2 >> BIN_BITS], 1u);
                st[sl2] = (unsigned short)((v2 & (CH_SIZE - 1)) | ((unsigned int)((g >> 62) & 1u) << CH_BITS));
            }
        }
    }
    __syncthreads();

    // coalesced flush: LDS region -> global, 16B vectors (slack beyond total never read)
    {
        const int tot = (int)s_total;
        const int nvec = (tot + 7) >> 3;               // 8 u16 per int4
        int4* __restrict__ dst = (int4*)(sorted + (size_t)k * RSTRIDE);  // RSTRIDE*2 % 16 == 0
        const int4* __restrict__ src = (const int4*)st;
        for (int i = threadIdx.x; i < nvec; i += 256) dst[i] = src[i];
    }
}

// sub-byte dirty mask from a 64-bit singles word: bit j = (byte j of m) != 0
__device__ __forceinline__ unsigned char subdirty8(unsigned long long m) {
    unsigned char b = 0;
    #pragma unroll
    for (int j = 0; j < 8; ++j) b |= (unsigned char)((((m >> (8 * j)) & 0xFFull) ? 1u : 0u) << j);
    return b;
}

// ---- per-chunk accumulate + decode + tmp/tgrp zeroing epilogue.
//      offs rows read directly (strided u16) -- no transpose kernel. ----
__global__ __launch_bounds__(1024) void k_accum(
    const unsigned short* __restrict__ offs,     // [SBLK][OROW]
    const unsigned short* __restrict__ sorted,
    const float* __restrict__ avars,
    unsigned int* __restrict__ packed,
    unsigned long long* __restrict__ avm,
    unsigned long long* __restrict__ svm,
    unsigned char* __restrict__ sgrp8,
    unsigned int* __restrict__ tmp,
    unsigned char* __restrict__ tgrp)
{
    __shared__ unsigned int acc[CH_SIZE];        // 16 KB
    __shared__ unsigned short row0[SBLK];        // 4 KB
    __shared__ unsigned short row1[SBLK];        // 4 KB
    const int c = blockIdx.x;                    // chunk 0..244
    const int r0 = 4 * c;
    const int r1 = (4 * c + 4 < NB) ? (4 * c + 4) : NB;
    for (int i = threadIdx.x; i < CH_SIZE; i += 1024) acc[i] = 0u;
    for (int i = threadIdx.x; i < SBLK; i += 1024) {   // strided gather of 2 offs columns
        row0[i] = offs[(size_t)i * OROW + r0];
        row1[i] = offs[(size_t)i * OROW + r1];
    }
    __syncthreads();
    for (int k = threadIdx.x; k < SBLK; k += 1024) {   // 2 regions per thread
        const int s0 = row0[k], s1 = row1[k];
        const unsigned short* seg = sorted + (size_t)k * RSTRIDE;  // 128B-aligned base
        int e = s0;
        for (; e < s1 && (e & 3); ++e) {               // head to 8B alignment
            unsigned int p = seg[e];
            atomicAdd(&acc[p & (CH_SIZE - 1)], 0x10000u | (p >> CH_BITS));
        }
        for (; e + 4 <= s1; e += 4) {                  // 4 entries per u64 load
            unsigned long long q = *(const unsigned long long*)(seg + e);
            #pragma unroll
            for (int j = 0; j < 4; ++j) {
                unsigned int p = (unsigned int)((q >> (16 * j)) & 0xFFFFu);
                atomicAdd(&acc[p & (CH_SIZE - 1)], 0x10000u | (p >> CH_BITS));
            }
        }
        for (; e < s1; ++e) {                          // tail
            unsigned int p = seg[e];
            atomicAdd(&acc[p & (CH_SIZE - 1)], 0x10000u | (p >> CH_BITS));
        }
    }
    __syncthreads();
    const int vbase = c << CH_BITS;
    for (int i = threadIdx.x; i < CH_SIZE; i += 1024) {
        int v = vbase + i;
        bool valid = v < Vn;
        unsigned int p = valid ? acc[i] : 0u;
        bool av = valid && (avars[v] != 0.0f);
        unsigned int cnt = p >> 16, pos = p & 0xFFFFu;
        bool sv = av && (pos == 0u || pos == cnt);    // deg == |sdeg|
        unsigned long long avb = __ballot(av);
        unsigned long long svb = __ballot(sv);
        if (valid) { packed[v] = p; tmp[v] = 0u; }    // tmp zeroed here (rides the pass)
        if ((threadIdx.x & 63) == 0) {                // word index < AVW (chunk-padded)
            avm[v >> 6] = avb;
            svm[v >> 6] = svb;
            sgrp8[v >> 6] = subdirty8(svb);           // 8-var-granular dirty bits
            tgrp[v >> 6] = 0;
        }
    }
}

// ---- iteration: function side. LDS sgrp8 filter then fine bitmask. ----
__device__ __forceinline__ void fire_one(unsigned long long g, int f,
                                         unsigned long long* __restrict__ gpack,
                                         const unsigned int* __restrict__ svm32,
                                         const unsigned char* __restrict__ s8,   // LDS
                                         unsigned int* __restrict__ tmp,
                                         unsigned char* __restrict__ tgrp)
{
    if ((long long)g >= 0) return;               // inactive (bit63 clear)
    unsigned int v0 = (unsigned int)(g & 0xFFFFFu);
    unsigned int v1 = (unsigned int)((g >> 20) & 0xFFFFFu);
    unsigned int v2 = (unsigned int)((g >> 40) & 0xFFFFFu);
    // LDS-resident 8-var-granular filter: no global transactions on the common path
    unsigned int h0 = (unsigned int)(s8[v0 >> 6] >> ((v0 >> 3) & 7u)) & 1u;
    unsigned int h1 = (unsigned int)(s8[v1 >> 6] >> ((v1 >> 3) & 7u)) & 1u;
    unsigned int h2 = (unsigned int)(s8[v2 >> 6] >> ((v2 >> 3) & 7u)) & 1u;
    if (!(h0 | h1 | h2)) return;
    unsigned int hit = ((svm32[v0 >> 5] >> (v0 & 31u)) |
                        (svm32[v1 >> 5] >> (v1 & 31u)) |
                        (svm32[v2 >> 5] >> (v2 & 31u))) & 1u;
    if (!hit) return;
    gpack[f] = g & ~(1ull << 63);                // function deactivates (single_f = 1)
    atomicAdd(&tmp[v0], 0x10000u | (unsigned int)((g >> 60) & 1u));
    atomicAdd(&tmp[v1], 0x10000u | (unsigned int)((g >> 61) & 1u));
    atomicAdd(&tmp[v2], 0x10000u | (unsigned int)((g >> 62) & 1u));
    tgrp[v0 >> 6] = 1; tgrp[v1 >> 6] = 1; tgrp[v2 >> 6] = 1;
}

static constexpr int FBLOCKS = 1024;             // grid-stride blocks (4/CU)

__global__ __launch_bounds__(256) void k_funcs(unsigned long long* __restrict__ gpack,
                        const unsigned int* __restrict__ svm32,
                        const unsigned char* __restrict__ sgrp8,
                        unsigned int* __restrict__ tmp,
                        unsigned char* __restrict__ tgrp)
{
    __shared__ __align__(16) unsigned char s8[AVW];        // 15.7 KB, AVW % 16 == 0
    for (int i = threadIdx.x; i < AVW / 16; i += 256)
        ((int4*)s8)[i] = ((const int4*)sgrp8)[i];
    __syncthreads();
    const int step = FBLOCKS * 256 * 8;
    for (int f = (blockIdx.x * 256 + threadIdx.x) * 8; f < Fn; f += step) {
        // Fn % 8 == 0: each 8-group is full
        ulonglong2 ga = *(const ulonglong2*)(gpack + f);   // 16B aligned
        ulonglong2 gb = *(const ulonglong2*)(gpack + f + 2);
        ulonglong2 gc = *(const ulonglong2*)(gpack + f + 4);
        ulonglong2 gd = *(const ulonglong2*)(gpack + f + 6);
        fire_one(ga.x, f,     gpack, svm32, s8, tmp, tgrp);
        fire_one(ga.y, f + 1, gpack, svm32, s8, tmp, tgrp);
        fire_one(gb.x, f + 2, gpack, svm32, s8, tmp, tgrp);
        fire_one(gb.y, f + 3, gpack, svm32, s8, tmp, tgrp);
        fire_one(gc.x, f + 4, gpack, svm32, s8, tmp, tgrp);
        fire_one(gc.y, f + 5, gpack, svm32, s8, tmp, tgrp);
        fire_one(gd.x, f + 6, gpack, svm32, s8, tmp, tgrp);
        fire_one(gd.y, f + 7, gpack, svm32, s8, tmp, tgrp);
    }
}

// ---- iteration: variable side. Clean-word early-exit; masks + sgrp8 refresh. ----
__global__ void k_update(unsigned int* __restrict__ packed,
                         unsigned int* __restrict__ tmp,
                         unsigned long long* __restrict__ avm,
                         unsigned long long* __restrict__ svm,
                         unsigned char* __restrict__ sgrp8,
                         unsigned char* __restrict__ tgrp,
                         float* __restrict__ deg, int write_deg)
{
    const int v = blockIdx.x * blockDim.x + threadIdx.x;
    const int lane = threadIdx.x & 63;
    const bool valid = v < Vn;
    unsigned long long avw = 0ull, svw = 0ull;
    unsigned char tg = 0;
    if (valid) {
        avw = avm[v >> 6]; svw = svm[v >> 6];          // wave-broadcast loads
        tg = tgrp[v >> 6];                             // wave-uniform dirty-group byte
    }
    // clean word: no fired updates, no singles to retire -> provably no state change
    if (!write_deg && !tg && svw == 0ull) return;
    const bool av_old = valid && ((avw >> lane) & 1ull);
    const bool sv     = valid && ((svw >> lane) & 1ull);
    const bool av_new = av_old && !sv;                  // av *= (1 - single_v)
    unsigned int p = 0u;
    if (valid) {
        p = packed[v];
        if (tg) {
            unsigned int tp = tmp[v];
            if (tp != 0u) {
                if (av_old) { p -= tp; packed[v] = p; } // deg -= seg*av (field-safe)
                tmp[v] = 0u;
            }
        }
    }
    const unsigned int c = p >> 16, pos = p & 0xFFFFu;
    const bool nsv = av_new && (pos == 0u || pos == c); // next single_v
    unsigned long long nsvb = __ballot(nsv);
    if (lane == 0 && valid) {
        svm[v >> 6] = nsvb;
        avm[v >> 6] = avw & ~svw;
        sgrp8[v >> 6] = subdirty8(nsvb);
        if (tg) tgrp[v >> 6] = 0;
    }
    if (write_deg && valid) deg[v] = (float)c;
}

extern "C" void kernel_launch(void* const* d_in, const int* in_sizes, int n_in,
                              void* d_out, int out_size, void* d_ws, size_t ws_size,
                              hipStream_t stream) {
    const int*   graph_map        = (const int*)d_in[0];   // row0 = vidx
    const float* edge_feature     = (const float*)d_in[1];
    const float* active_variables = (const float*)d_in[2];
    const float* active_functions = (const float*)d_in[3];
    const int* vidx = graph_map;

    float* deg = (float*)d_out;
    char* ws = (char*)d_ws;
    size_t off = 0;
    auto alloc = [&](size_t bytes) -> void* {
        void* p = ws + off; off += (bytes + 255) & ~(size_t)255; return p;
    };
    unsigned long long* gpack = (unsigned long long*)alloc(8ull * Fn);            // 33.6 MB
    unsigned int* packed      = (unsigned int*)alloc(4ull * Vn);                  //  4.0 MB
    unsigned long long* avm   = (unsigned long long*)alloc(8ull * AVW);           //  125 KB
    unsigned long long* svm   = (unsigned long long*)alloc(8ull * AVW);           //  125 KB
    unsigned char* sgrp8      = (unsigned char*)alloc(AVW);                       // 15.7 KB
    unsigned char* tgrp       = (unsigned char*)alloc(AVW);                       // 15.7 KB
    unsigned short* offs      = (unsigned short*)alloc(2ull * SBLK * OROW);       //  4.2 MB
    unsigned short* sorted    = (unsigned short*)alloc(2ull * SBLK * RSTRIDE);    // 25.4 MB
    unsigned int* tmp         = (unsigned int*)alloc(4ull * Vn);                  //  4.0 MB
    // total ~71.5 MB

    const int BS = 256;
    const int gV = (Vn + BS - 1) / BS;

    k_pack_sort<<<SBLK, 256, 0, stream>>>(vidx, edge_feature, active_functions,
                                          gpack, offs, sorted);
    k_accum<<<NCH, 1024, 0, stream>>>(offs, sorted, active_variables, packed,
                                      avm, svm, sgrp8, tmp, tgrp);
    for (int t = 0; t < Tn; ++t) {
        k_funcs<<<FBLOCKS, BS, 0, stream>>>(gpack, (const unsigned int*)svm, sgrp8, tmp, tgrp);
        k_update<<<gV, BS, 0, stream>>>(packed, tmp, avm, svm, sgrp8, tgrp, deg, (t == Tn - 1) ? 1 : 0);
    }
}